// Round 13
// baseline (870.883 us; speedup 1.0000x reference)
//
#include <hip/hip_runtime.h>
#include <math.h>

// Sinkhorn divergence (geomloss 'sinkhorn', debias=True) with quaternion
// geodesic cost, B=8, P=2048, D=4.
//
// R13 = all-4-decode. Calibrated costs: decode softmin d ~ 7.95 us/pass,
// recompute r ~ 15.75 (R10/R11/R12 fits). 4 u16 mats = exactly 256 MiB =
// (likely) the whole ws; the pot ping-pong moves into the x/y input buffers
// (dead after precompute in all-decode mode; harness restores d_in before
// every launch so in-launch writes are safe) and wx/wy are transformed
// in-place to log2(w) (loss kernel inverts via exp2). Floor 4d ~ 31.8
// us/pass, no decode/recompute tail imbalance (uniform waves).
// Fallback: ws < 256 MiB -> the PROVEN R11 3/2/1/0-mat path verbatim.

#define BATCH 8
#define NP    2048
#define NPOT  (BATCH * NP)                 // 16384 floats per potential array
#define MAT_ELEMS  ((size_t)BATCH * NP * NP)   // 33,554,432 u16 per matrix
#define MAT_DWORDS (MAT_ELEMS / 2)             // 16,777,216 dwords
#define MAT_BYTES  (MAT_ELEMS * 2)             // 67,108,864 bytes

__device__ __forceinline__ float bcastf(float v) {
  return __int_as_float(__builtin_amdgcn_readfirstlane(__float_as_int(v)));
}

// ---------------------------------------------------------------------------
// Precompute: C as u16 codes a = round(2*acos(|<q,p>|) * 65535/pi).
// m=0: Cxy (rows=x cols=y); m=1: Cyx; m=2: Cxx; m=3: Cyy.
// ---------------------------------------------------------------------------
__global__ __launch_bounds__(512, 8) void precompute_mats(
    const float* __restrict__ x, const float* __restrict__ y,
    unsigned int* __restrict__ mats,
    float P0, float P1, float P2, float P3)
{
  const int bid  = blockIdx.x;          // grid = n_mats * 256
  const int m    = bid >> 8;
  const int b    = (bid >> 5) & 7;
  const int rg   = bid & 31;
  const int tid  = threadIdx.x;
  const int lane = tid & 63;

  __shared__ float4 Pts[NP];

  const float4* rowp; const float4* colp;
  if (m == 0)      { rowp = (const float4*)x; colp = (const float4*)y; }
  else if (m == 1) { rowp = (const float4*)y; colp = (const float4*)x; }
  else if (m == 2) { rowp = (const float4*)x; colp = (const float4*)x; }
  else             { rowp = (const float4*)y; colp = (const float4*)y; }
  rowp += b * NP; colp += b * NP;

  #pragma unroll
  for (int t = 0; t < 4; ++t)
    Pts[tid + t * 512] = colp[tid + t * 512];
  __syncthreads();

  const int wvu = __builtin_amdgcn_readfirstlane(tid >> 6);
  const int i0  = rg * 64 + wvu * 8;
  float qx[8], qy[8], qz[8], qw[8];
  #pragma unroll
  for (int r = 0; r < 8; ++r) {
    const float4 t4 = rowp[i0 + r];
    qx[r] = bcastf(t4.x); qy[r] = bcastf(t4.y);
    qz[r] = bcastf(t4.z); qw[r] = bcastf(t4.w);
  }

  unsigned int* obase = mats + (size_t)m * MAT_DWORDS
                      + (((size_t)(b * NP + i0)) << 10);

  for (int t = 0; t < 16; ++t) {
    const int j = t * 64 + lane;
    const float4 p0 = Pts[j];
    const float4 p1 = Pts[j + 1024];
    #pragma unroll
    for (int r = 0; r < 8; ++r) {
      float dt0 = fmaf(qx[r], p0.x, fmaf(qy[r], p0.y,
                   fmaf(qz[r], p0.z, qw[r] * p0.w)));
      float dt1 = fmaf(qx[r], p1.x, fmaf(qy[r], p1.y,
                   fmaf(qz[r], p1.z, qw[r] * p1.w)));
      const float u0 = fmaxf(1.0f - fabsf(dt0), 1e-6f);
      const float u1 = fmaxf(1.0f - fabsf(dt1), 1e-6f);
      const float s0 = __builtin_amdgcn_sqrtf(u0);
      const float s1 = __builtin_amdgcn_sqrtf(u1);
      const float g0 = fmaf(fmaf(fmaf(P3, u0, P2), u0, P1), u0, P0);
      const float g1 = fmaf(fmaf(fmaf(P3, u1, P2), u1, P1), u1, P0);
      const unsigned int a0 = (unsigned int)fmaf(s0, g0, 0.5f);  // <= 65533
      const unsigned int a1 = (unsigned int)fmaf(s1, g1, 0.5f);
      obase[(r << 10) + j] = a0 | (a1 << 16);
    }
  }
}

// In-place wx/wy -> log2(w) (mode-4 only; saves per-pass staging log).
__global__ __launch_bounds__(512) void prep_logw(float* wx, float* wy)
{
  const int g = blockIdx.x * 512 + threadIdx.x;   // grid 64*512 = 32768
  if (g < NPOT)            wx[g]         = __builtin_amdgcn_logf(wx[g]);
  else                     wy[g - NPOT]  = __builtin_amdgcn_logf(wy[g - NPOT]);
}

// ---------------------------------------------------------------------------
// Mode-4 pass kernel: ALL four softmins decode from u16 mats. LDS = 8 KB.
// ---------------------------------------------------------------------------
__global__ __launch_bounds__(512, 8) void sink_pass_dec(
    const float* __restrict__ lwx, const float* __restrict__ lwy, // log2 w
    const unsigned int* __restrict__ mats,
    const float* __restrict__ pot_old, float* __restrict__ pot_new,
    float eps, float c1, float seed_s, float kdec, int use_avg)
{
  const int bid  = blockIdx.x;         // grid 1024: s(4) x b(8) x rg(32)
  const int s    = bid >> 8;
  const int b    = (bid >> 5) & 7;
  const int rg   = bid & 31;
  const int tid  = threadIdx.x;
  const int lane = tid & 63;

  __shared__ float Hs[NP];             // 8 KB only

  const float* colw; const float* colpot;
  if (s == 0)      { colw = lwy; colpot = pot_old + 1 * NPOT; }
  else if (s == 1) { colw = lwx; colpot = pot_old + 0 * NPOT; }
  else if (s == 2) { colw = lwx; colpot = pot_old + 2 * NPOT; }
  else             { colw = lwy; colpot = pot_old + 3 * NPOT; }
  colw += b * NP; colpot += b * NP;

  #pragma unroll
  for (int t = 0; t < 4; ++t) {
    const int idx = tid + t * 512;
    Hs[idx] = fmaf(colpot[idx], c1, colw[idx]);   // c1==0 on init: x*0 == 0
  }
  __syncthreads();

  const int wvu = __builtin_amdgcn_readfirstlane(tid >> 6);
  const int i0  = rg * 64 + wvu * 8;
  const int oidx = s * NPOT + b * NP + i0;
  float mh[8];
  #pragma unroll
  for (int r = 0; r < 8; ++r)
    mh[r] = bcastf(pot_old[oidx + r] * seed_s);

  const unsigned int* mrow = mats + (size_t)s * MAT_DWORDS
                           + (((size_t)(b * NP + i0)) << 10);

  float ss[8] = {0.f, 0.f, 0.f, 0.f, 0.f, 0.f, 0.f, 0.f};
  for (int t = 0; t < 16; ++t) {
    const int j = t * 64 + lane;
    const float h0 = Hs[j];
    const float h1 = Hs[j + 1024];
    #pragma unroll
    for (int r = 0; r < 8; ++r) {
      const unsigned int U = mrow[(r << 10) + j];
      ss[r] += __builtin_amdgcn_exp2f(fmaf((float)(U & 0xFFFFu), -kdec, h0 - mh[r]))
             + __builtin_amdgcn_exp2f(fmaf((float)(U >> 16),     -kdec, h1 - mh[r]));
    }
  }
  #pragma unroll
  for (int r = 0; r < 8; ++r) {
    float sv = ss[r];
    #pragma unroll
    for (int off = 32; off >= 1; off >>= 1)
      sv += __shfl_xor(sv, off, 64);
    ss[r] = sv;
  }
  // safety net: two-phase decode re-sweep for out-of-band rows
  #pragma unroll
  for (int r = 0; r < 8; ++r) {
    const bool good = (ss[r] >= 8.6736174e-19f) && (ss[r] <= 1.1529215e18f);
    if (!good) {
      float mv = -3.0e38f;
      for (int t = 0; t < 16; ++t) {
        const int j = t * 64 + lane;
        const unsigned int U = mrow[(r << 10) + j];
        mv = fmaxf(mv, fmaf((float)(U & 0xFFFFu), -kdec, Hs[j]));
        mv = fmaxf(mv, fmaf((float)(U >> 16),     -kdec, Hs[j + 1024]));
      }
      #pragma unroll
      for (int off = 32; off >= 1; off >>= 1)
        mv = fmaxf(mv, __shfl_xor(mv, off, 64));
      mh[r] = mv;
      float sv = 0.0f;
      for (int t = 0; t < 16; ++t) {
        const int j = t * 64 + lane;
        const unsigned int U = mrow[(r << 10) + j];
        sv += __builtin_amdgcn_exp2f(fmaf((float)(U & 0xFFFFu), -kdec, Hs[j] - mh[r]))
            + __builtin_amdgcn_exp2f(fmaf((float)(U >> 16),     -kdec, Hs[j + 1024] - mh[r]));
      }
      #pragma unroll
      for (int off = 32; off >= 1; off >>= 1)
        sv += __shfl_xor(sv, off, 64);
      ss[r] = sv;
    }
  }

  if (lane == 0) {
    #pragma unroll
    for (int r = 0; r < 8; ++r) {
      float res = -eps * 0.69314718055994531f
                * (mh[r] + __builtin_amdgcn_logf(ss[r]));
      if (use_avg) res = 0.5f * (pot_old[oidx + r] + res);
      pot_new[oidx + r] = res;
    }
  }
}

// ---------------------------------------------------------------------------
// Fallback pass kernel (R11 verbatim, proven 598 us)
// ---------------------------------------------------------------------------
__global__ __launch_bounds__(512, 8) void sink_pass_r11(
    const float* __restrict__ x, const float* __restrict__ y,
    const float* __restrict__ wx, const float* __restrict__ wy,
    const unsigned int* __restrict__ mats, int n_mats,
    const float* __restrict__ pot_old, float* __restrict__ pot_new,
    float eps, float c1, float seed_s, float kdec,
    float B0, float B1, float B2, float B3, int use_avg)
{
  const int bid  = blockIdx.x;
  const int s    = bid >> 8;
  const int b    = (bid >> 5) & 7;
  const int rg   = bid & 31;
  const int tid  = threadIdx.x;
  const int lane = tid & 63;

  __shared__ float4 Pts[NP];
  __shared__ float  Hs[NP];

  const float4* colp; const float* colw; const float* colpot; const float4* rowp;
  if (s == 0)      { colp=(const float4*)y; colw=wy; colpot=pot_old+1*NPOT; rowp=(const float4*)x; }
  else if (s == 1) { colp=(const float4*)x; colw=wx; colpot=pot_old+0*NPOT; rowp=(const float4*)y; }
  else if (s == 2) { colp=(const float4*)x; colw=wx; colpot=pot_old+2*NPOT; rowp=(const float4*)x; }
  else             { colp=(const float4*)y; colw=wy; colpot=pot_old+3*NPOT; rowp=(const float4*)y; }
  colp += b * NP; colw += b * NP; colpot += b * NP;

  const bool use_mat = (s < n_mats);

  if (use_mat) {
    #pragma unroll
    for (int t = 0; t < 4; ++t) {
      const int idx = tid + t * 512;
      Hs[idx] = fmaf(colpot[idx], c1, __builtin_amdgcn_logf(colw[idx]));
    }
  } else {
    #pragma unroll
    for (int t = 0; t < 4; ++t) {
      const int idx = tid + t * 512;
      Pts[idx] = colp[idx];
      Hs[idx] = fmaf(colpot[idx], c1, __builtin_amdgcn_logf(colw[idx]));
    }
  }
  __syncthreads();

  const int wvu = __builtin_amdgcn_readfirstlane(tid >> 6);
  const int i0  = rg * 64 + wvu * 8;
  const int oidx = s * NPOT + b * NP + i0;
  float mh[8];
  #pragma unroll
  for (int r = 0; r < 8; ++r)
    mh[r] = bcastf(pot_old[oidx + r] * seed_s);

  float ss[8] = {0.f, 0.f, 0.f, 0.f, 0.f, 0.f, 0.f, 0.f};

  if (use_mat) {
    const unsigned int* mrow = mats + (size_t)s * MAT_DWORDS
                             + (((size_t)(b * NP + i0)) << 10);
    for (int t = 0; t < 16; ++t) {
      const int j = t * 64 + lane;
      const float h0 = Hs[j];
      const float h1 = Hs[j + 1024];
      #pragma unroll
      for (int r = 0; r < 8; ++r) {
        const unsigned int U = mrow[(r << 10) + j];
        ss[r] += __builtin_amdgcn_exp2f(fmaf((float)(U & 0xFFFFu), -kdec, h0 - mh[r]))
               + __builtin_amdgcn_exp2f(fmaf((float)(U >> 16),     -kdec, h1 - mh[r]));
      }
    }
    #pragma unroll
    for (int r = 0; r < 8; ++r) {
      float sv = ss[r];
      #pragma unroll
      for (int off = 32; off >= 1; off >>= 1)
        sv += __shfl_xor(sv, off, 64);
      ss[r] = sv;
    }
    #pragma unroll
    for (int r = 0; r < 8; ++r) {
      const bool good = (ss[r] >= 8.6736174e-19f) && (ss[r] <= 1.1529215e18f);
      if (!good) {
        float mv = -3.0e38f;
        for (int t = 0; t < 16; ++t) {
          const int j = t * 64 + lane;
          const unsigned int U = mrow[(r << 10) + j];
          mv = fmaxf(mv, fmaf((float)(U & 0xFFFFu), -kdec, Hs[j]));
          mv = fmaxf(mv, fmaf((float)(U >> 16),     -kdec, Hs[j + 1024]));
        }
        #pragma unroll
        for (int off = 32; off >= 1; off >>= 1)
          mv = fmaxf(mv, __shfl_xor(mv, off, 64));
        mh[r] = mv;
        float sv = 0.0f;
        for (int t = 0; t < 16; ++t) {
          const int j = t * 64 + lane;
          const unsigned int U = mrow[(r << 10) + j];
          sv += __builtin_amdgcn_exp2f(fmaf((float)(U & 0xFFFFu), -kdec, Hs[j] - mh[r]))
              + __builtin_amdgcn_exp2f(fmaf((float)(U >> 16),     -kdec, Hs[j + 1024] - mh[r]));
        }
        #pragma unroll
        for (int off = 32; off >= 1; off >>= 1)
          sv += __shfl_xor(sv, off, 64);
        ss[r] = sv;
      }
    }
  } else {
    float qx[8], qy[8], qz[8], qw[8];
    #pragma unroll
    for (int r = 0; r < 8; ++r) {
      const float4 t4 = rowp[b * NP + i0 + r];
      qx[r] = bcastf(t4.x); qy[r] = bcastf(t4.y);
      qz[r] = bcastf(t4.z); qw[r] = bcastf(t4.w);
    }
    for (int t = 0; t < 16; ++t) {
      float4 p[2]; float h[2];
      #pragma unroll
      for (int cc = 0; cc < 2; ++cc) {
        const int j = (t * 2 + cc) * 64 + lane;
        p[cc] = Pts[j];
        h[cc] = Hs[j];
      }
      #pragma unroll
      for (int r = 0; r < 8; ++r) {
        #pragma unroll
        for (int cc = 0; cc < 2; ++cc) {
          const float dt = fmaf(qx[r], p[cc].x,
                            fmaf(qy[r], p[cc].y,
                             fmaf(qz[r], p[cc].z, qw[r] * p[cc].w)));
          const float u  = fmaxf(1.0f - fabsf(dt), 1e-6f);
          const float sq = __builtin_amdgcn_sqrtf(u);
          const float pl = fmaf(fmaf(fmaf(B3, u, B2), u, B1), u, B0);
          const float v  = fmaf(sq, -pl, h[cc]);
          ss[r] += __builtin_amdgcn_exp2f(v - mh[r]);
        }
      }
    }
    #pragma unroll
    for (int r = 0; r < 8; ++r) {
      float sv = ss[r];
      #pragma unroll
      for (int off = 32; off >= 1; off >>= 1)
        sv += __shfl_xor(sv, off, 64);
      ss[r] = sv;
    }
    #pragma unroll
    for (int r = 0; r < 8; ++r) {
      const bool good = (ss[r] >= 8.6736174e-19f) && (ss[r] <= 1.1529215e18f);
      if (!good) {
        float mv = -3.0e38f;
        for (int t = 0; t < 32; ++t) {
          const int j = t * 64 + lane;
          const float4 p = Pts[j];
          const float dt = fmaf(qx[r], p.x,
                            fmaf(qy[r], p.y, fmaf(qz[r], p.z, qw[r] * p.w)));
          const float u  = fmaxf(1.0f - fabsf(dt), 1e-6f);
          const float sq = __builtin_amdgcn_sqrtf(u);
          const float pl = fmaf(fmaf(fmaf(B3, u, B2), u, B1), u, B0);
          mv = fmaxf(mv, fmaf(sq, -pl, Hs[j]));
        }
        #pragma unroll
        for (int off = 32; off >= 1; off >>= 1)
          mv = fmaxf(mv, __shfl_xor(mv, off, 64));
        mh[r] = mv;
        float sv = 0.0f;
        for (int t = 0; t < 32; ++t) {
          const int j = t * 64 + lane;
          const float4 p = Pts[j];
          const float dt = fmaf(qx[r], p.x,
                            fmaf(qy[r], p.y, fmaf(qz[r], p.z, qw[r] * p.w)));
          const float u  = fmaxf(1.0f - fabsf(dt), 1e-6f);
          const float sq = __builtin_amdgcn_sqrtf(u);
          const float pl = fmaf(fmaf(fmaf(B3, u, B2), u, B1), u, B0);
          sv += __builtin_amdgcn_exp2f(fmaf(sq, -pl, Hs[j]) - mh[r]);
        }
        #pragma unroll
        for (int off = 32; off >= 1; off >>= 1)
          sv += __shfl_xor(sv, off, 64);
        ss[r] = sv;
      }
    }
  }

  if (lane == 0) {
    #pragma unroll
    for (int r = 0; r < 8; ++r) {
      float res = -eps * 0.69314718055994531f
                * (mh[r] + __builtin_amdgcn_logf(ss[r]));
      if (use_avg) res = 0.5f * (pot_old[oidx + r] + res);
      pot_new[oidx + r] = res;
    }
  }
}

__global__ __launch_bounds__(256) void loss_kernel(
    const float* __restrict__ pot, const float* __restrict__ wx,
    const float* __restrict__ wy, float* __restrict__ out, int w_is_log)
{
  const int tid = threadIdx.x;
  double acc = 0.0;
  for (int idx = tid; idx < NPOT; idx += 256) {
    const float wxe = w_is_log ? __builtin_amdgcn_exp2f(wx[idx]) : wx[idx];
    const float wye = w_is_log ? __builtin_amdgcn_exp2f(wy[idx]) : wy[idx];
    acc += (double)wxe * ((double)pot[0 * NPOT + idx] - (double)pot[2 * NPOT + idx]);
    acc += (double)wye * ((double)pot[1 * NPOT + idx] - (double)pot[3 * NPOT + idx]);
  }
  #pragma unroll
  for (int off = 32; off >= 1; off >>= 1)
    acc += __shfl_xor(acc, off, 64);
  __shared__ double wsum[4];
  if ((tid & 63) == 0) wsum[tid >> 6] = acc;
  __syncthreads();
  if (tid == 0)
    out[0] = (float)((wsum[0] + wsum[1] + wsum[2] + wsum[3]) / (double)BATCH);
}

extern "C" void kernel_launch(void* const* d_in, const int* in_sizes, int n_in,
                              void* d_out, int out_size, void* d_ws, size_t ws_size,
                              hipStream_t stream)
{
  float* x  = (float*)d_in[0];
  float* y  = (float*)d_in[1];
  float* wx = (float*)d_in[2];
  float* wy = (float*)d_in[3];

  const size_t potBytes = (size_t)2 * 4 * NPOT * 4;   // 524,288
  const bool mode4 = (ws_size >= 4 * MAT_BYTES);      // 256 MiB of mats

  int n_mats;
  unsigned int* mats = (unsigned int*)d_ws;
  float* pot[2];
  if (mode4) {
    n_mats = 4;
    pot[0] = x;                       // x buffer: 65536 floats == 4*NPOT
    pot[1] = y;                       // y buffer: same size
  } else {
    n_mats = 0;
    if      (ws_size >= 3 * MAT_BYTES + potBytes) n_mats = 3;
    else if (ws_size >= 2 * MAT_BYTES + potBytes) n_mats = 2;
    else if (ws_size >= 1 * MAT_BYTES + potBytes) n_mats = 1;
    pot[0] = (float*)((char*)d_ws + (size_t)n_mats * MAT_BYTES);
    pot[1] = pot[0] + 4 * NPOT;
  }

  // geomloss epsilon_schedule(p=2, diameter=3.15, blur=0.01, scaling=0.5)
  double eps_list[16]; int ne = 0;
  eps_list[ne++] = 3.15 * 3.15;
  const double stop = 2.0 * log(0.01), step = 2.0 * log(0.5);
  for (double e = 2.0 * log(3.15); e > stop; e += step) eps_list[ne++] = exp(e);
  eps_list[ne++] = 0.01 * 0.01;   // ne == 11

  const double LOG2E = 1.4426950408889634;
  const double PI    = 3.14159265358979323846;
  const double b0 = 1.4141461, b1 = 0.1197803, b2 = 0.0180731, b3 = 0.0187293;
  const dim3 grid(1024), blkPass(512), blkLoss(256);
  int cur = 0;

  if (n_mats > 0) {
    const double S2 = 2.0 * 65535.0 / PI;
    hipLaunchKernelGGL(precompute_mats, dim3(n_mats * 256), blkPass, 0, stream,
        x, y, mats,
        (float)(b0 * S2), (float)(b1 * S2), (float)(b2 * S2), (float)(b3 * S2));
  }
  if (mode4) {
    hipLaunchKernelGGL(prep_logw, dim3(64), blkPass, 0, stream, wx, wy);
  }

  auto launch_pass = [&](double e, float c1f, float seedf, int avg) {
    const double sc = 2.0 * LOG2E / e;
    const double kd = (PI / 65535.0) * (LOG2E / e);
    if (mode4) {
      hipLaunchKernelGGL(sink_pass_dec, grid, blkPass, 0, stream,
          wx, wy, mats, pot[cur], pot[1 - cur],
          (float)e, c1f, seedf, (float)kd, avg);
    } else {
      hipLaunchKernelGGL(sink_pass_r11, grid, blkPass, 0, stream,
          x, y, wx, wy, mats, n_mats, pot[cur], pot[1 - cur],
          (float)e, c1f, seedf, (float)kd,
          (float)(b0 * sc), (float)(b1 * sc), (float)(b2 * sc), (float)(b3 * sc), avg);
    }
    cur ^= 1;
  };

  // init pass: no potential in h, m_hat = 0, replace-mode
  launch_pass(eps_list[0], 0.0f, 0.0f, 0);
  // annealing loop, averaging update
  for (int k = 0; k < ne; ++k) {
    const double e = eps_list[k];
    launch_pass(e, (float)(LOG2E / e), (float)(-LOG2E / e), 1);
  }
  // final extrapolation, replace-mode
  {
    const double e = eps_list[ne - 1];
    launch_pass(e, (float)(LOG2E / e), (float)(-LOG2E / e), 0);
  }

  hipLaunchKernelGGL(loss_kernel, dim3(1), blkLoss, 0, stream,
      pot[cur], wx, wy, (float*)d_out, mode4 ? 1 : 0);
}

// Round 14
// 612.271 us; speedup vs baseline: 1.4224x; 1.4224x over previous
//
#include <hip/hip_runtime.h>
#include <math.h>

// Sinkhorn divergence (geomloss 'sinkhorn', debias=True) with quaternion
// geodesic cost, B=8, P=2048, D=4.
//
// R14 = R11 (proven best, 598 us; 3 u16 mats + 1 recompute) with the mat
// loads widened 4B->16B per lane (uint4, 8 u16 cols/lane-iter). Evidence:
// mat streams miss L3 at a structural ~52% for any footprint 128-256 MiB
// (R11/R12/R13) and saturate ~4.5 TB/s demand; the 6.3 TB/s ceiling was
// measured at 16 B/lane -- dword loads (256 B/wave-instr) are likely
// transaction-rate limited. Layout (dword d = cols (d, d+1024)) unchanged;
// only the reader widens. Host tiering capped at n_mats=3 (k=3 balances
// t_mem ~ 33.5us vs t_valu ~ 29.2us; k=4 proven memory-bound, k=2 proven
// compute-bound).

#define BATCH 8
#define NP    2048
#define NPOT  (BATCH * NP)                 // 16384 floats per potential array
#define MAT_ELEMS  ((size_t)BATCH * NP * NP)   // 33,554,432 u16 per matrix
#define MAT_DWORDS (MAT_ELEMS / 2)             // 16,777,216 dwords
#define MAT_BYTES  (MAT_ELEMS * 2)             // 67,108,864 bytes

__device__ __forceinline__ float bcastf(float v) {
  return __int_as_float(__builtin_amdgcn_readfirstlane(__float_as_int(v)));
}

// ---------------------------------------------------------------------------
// Precompute: C as u16 codes a = round(2*acos(|<q,p>|) * 65535/pi).
// m=0: Cxy (rows=x cols=y); m=1: Cyx; m=2: Cxx.
// ---------------------------------------------------------------------------
__global__ __launch_bounds__(512, 8) void precompute_mats(
    const float* __restrict__ x, const float* __restrict__ y,
    unsigned int* __restrict__ mats,
    float P0, float P1, float P2, float P3)
{
  const int bid  = blockIdx.x;          // grid = n_mats * 256
  const int m    = bid >> 8;
  const int b    = (bid >> 5) & 7;
  const int rg   = bid & 31;
  const int tid  = threadIdx.x;
  const int lane = tid & 63;

  __shared__ float4 Pts[NP];

  const float4* rowp; const float4* colp;
  if (m == 0)      { rowp = (const float4*)x; colp = (const float4*)y; }
  else if (m == 1) { rowp = (const float4*)y; colp = (const float4*)x; }
  else             { rowp = (const float4*)x; colp = (const float4*)x; }
  rowp += b * NP; colp += b * NP;

  #pragma unroll
  for (int t = 0; t < 4; ++t)
    Pts[tid + t * 512] = colp[tid + t * 512];
  __syncthreads();

  const int wvu = __builtin_amdgcn_readfirstlane(tid >> 6);
  const int i0  = rg * 64 + wvu * 8;
  float qx[8], qy[8], qz[8], qw[8];
  #pragma unroll
  for (int r = 0; r < 8; ++r) {
    const float4 t4 = rowp[i0 + r];
    qx[r] = bcastf(t4.x); qy[r] = bcastf(t4.y);
    qz[r] = bcastf(t4.z); qw[r] = bcastf(t4.w);
  }

  unsigned int* obase = mats + (size_t)m * MAT_DWORDS
                      + (((size_t)(b * NP + i0)) << 10);

  for (int t = 0; t < 16; ++t) {
    const int j = t * 64 + lane;
    const float4 p0 = Pts[j];
    const float4 p1 = Pts[j + 1024];
    #pragma unroll
    for (int r = 0; r < 8; ++r) {
      float dt0 = fmaf(qx[r], p0.x, fmaf(qy[r], p0.y,
                   fmaf(qz[r], p0.z, qw[r] * p0.w)));
      float dt1 = fmaf(qx[r], p1.x, fmaf(qy[r], p1.y,
                   fmaf(qz[r], p1.z, qw[r] * p1.w)));
      const float u0 = fmaxf(1.0f - fabsf(dt0), 1e-6f);
      const float u1 = fmaxf(1.0f - fabsf(dt1), 1e-6f);
      const float s0 = __builtin_amdgcn_sqrtf(u0);
      const float s1 = __builtin_amdgcn_sqrtf(u1);
      const float g0 = fmaf(fmaf(fmaf(P3, u0, P2), u0, P1), u0, P0);
      const float g1 = fmaf(fmaf(fmaf(P3, u1, P2), u1, P1), u1, P0);
      const unsigned int a0 = (unsigned int)fmaf(s0, g0, 0.5f);  // <= 65533
      const unsigned int a1 = (unsigned int)fmaf(s1, g1, 0.5f);
      obase[(r << 10) + j] = a0 | (a1 << 16);
    }
  }
}

// ---------------------------------------------------------------------------
// Pass kernel: s < n_mats -> u16 decode (uint4-wide); else R10 recompute.
// ---------------------------------------------------------------------------
__global__ __launch_bounds__(512, 8) void sink_pass_r14(
    const float* __restrict__ x, const float* __restrict__ y,
    const float* __restrict__ wx, const float* __restrict__ wy,
    const unsigned int* __restrict__ mats, int n_mats,
    const float* __restrict__ pot_old, float* __restrict__ pot_new,
    float eps, float c1, float seed_s, float kdec,
    float B0, float B1, float B2, float B3, int use_avg)
{
  const int bid  = blockIdx.x;         // grid 1024: s(4) x b(8) x rg(32)
  const int s    = bid >> 8;
  const int b    = (bid >> 5) & 7;
  const int rg   = bid & 31;
  const int tid  = threadIdx.x;
  const int lane = tid & 63;

  __shared__ float4 Pts[NP];   // 32 KB (recompute path only)
  __shared__ float  Hs[NP];    //  8 KB

  const float4* colp; const float* colw; const float* colpot; const float4* rowp;
  if (s == 0)      { colp=(const float4*)y; colw=wy; colpot=pot_old+1*NPOT; rowp=(const float4*)x; }
  else if (s == 1) { colp=(const float4*)x; colw=wx; colpot=pot_old+0*NPOT; rowp=(const float4*)y; }
  else if (s == 2) { colp=(const float4*)x; colw=wx; colpot=pot_old+2*NPOT; rowp=(const float4*)x; }
  else             { colp=(const float4*)y; colw=wy; colpot=pot_old+3*NPOT; rowp=(const float4*)y; }
  colp += b * NP; colw += b * NP; colpot += b * NP;

  const bool use_mat = (s < n_mats);

  if (use_mat) {
    #pragma unroll
    for (int t = 0; t < 4; ++t) {
      const int idx = tid + t * 512;
      Hs[idx] = fmaf(colpot[idx], c1, __builtin_amdgcn_logf(colw[idx]));
    }
  } else {
    #pragma unroll
    for (int t = 0; t < 4; ++t) {
      const int idx = tid + t * 512;
      Pts[idx] = colp[idx];
      Hs[idx] = fmaf(colpot[idx], c1, __builtin_amdgcn_logf(colw[idx]));
    }
  }
  __syncthreads();

  const int wvu = __builtin_amdgcn_readfirstlane(tid >> 6);
  const int i0  = rg * 64 + wvu * 8;
  const int oidx = s * NPOT + b * NP + i0;
  float mh[8];
  #pragma unroll
  for (int r = 0; r < 8; ++r)
    mh[r] = bcastf(pot_old[oidx + r] * seed_s);

  float ss[8] = {0.f, 0.f, 0.f, 0.f, 0.f, 0.f, 0.f, 0.f};

  if (use_mat) {
    // -------- u16 decode path, 16 B/lane loads (8 cols per lane-iter) -----
    const uint4* mrow4 = (const uint4*)(mats + (size_t)s * MAT_DWORDS
                             + (((size_t)(b * NP + i0)) << 10));
    for (int t = 0; t < 4; ++t) {
      const int j = t * 256 + (lane << 2);       // first dword-col of this lane
      const float4 hA = *(const float4*)&Hs[j];         // cols j..j+3
      const float4 hB = *(const float4*)&Hs[j + 1024];  // cols +1024
      #pragma unroll
      for (int r = 0; r < 8; ++r) {
        const uint4 U = mrow4[(r << 8) + t * 64 + lane];
        const float m8 = mh[r];
        ss[r] += __builtin_amdgcn_exp2f(fmaf((float)(U.x & 0xFFFFu), -kdec, hA.x - m8))
               + __builtin_amdgcn_exp2f(fmaf((float)(U.x >> 16),     -kdec, hB.x - m8))
               + __builtin_amdgcn_exp2f(fmaf((float)(U.y & 0xFFFFu), -kdec, hA.y - m8))
               + __builtin_amdgcn_exp2f(fmaf((float)(U.y >> 16),     -kdec, hB.y - m8))
               + __builtin_amdgcn_exp2f(fmaf((float)(U.z & 0xFFFFu), -kdec, hA.z - m8))
               + __builtin_amdgcn_exp2f(fmaf((float)(U.z >> 16),     -kdec, hB.z - m8))
               + __builtin_amdgcn_exp2f(fmaf((float)(U.w & 0xFFFFu), -kdec, hA.w - m8))
               + __builtin_amdgcn_exp2f(fmaf((float)(U.w >> 16),     -kdec, hB.w - m8));
      }
    }
    #pragma unroll
    for (int r = 0; r < 8; ++r) {
      float sv = ss[r];
      #pragma unroll
      for (int off = 32; off >= 1; off >>= 1)
        sv += __shfl_xor(sv, off, 64);
      ss[r] = sv;
    }
    // safety net: two-phase decode re-sweep for out-of-band rows
    #pragma unroll
    for (int r = 0; r < 8; ++r) {
      const bool good = (ss[r] >= 8.6736174e-19f) && (ss[r] <= 1.1529215e18f);
      if (!good) {
        float mv = -3.0e38f;
        for (int t = 0; t < 4; ++t) {
          const int j = t * 256 + (lane << 2);
          const float4 hA = *(const float4*)&Hs[j];
          const float4 hB = *(const float4*)&Hs[j + 1024];
          const uint4 U = mrow4[(r << 8) + t * 64 + lane];
          mv = fmaxf(mv, fmaf((float)(U.x & 0xFFFFu), -kdec, hA.x));
          mv = fmaxf(mv, fmaf((float)(U.x >> 16),     -kdec, hB.x));
          mv = fmaxf(mv, fmaf((float)(U.y & 0xFFFFu), -kdec, hA.y));
          mv = fmaxf(mv, fmaf((float)(U.y >> 16),     -kdec, hB.y));
          mv = fmaxf(mv, fmaf((float)(U.z & 0xFFFFu), -kdec, hA.z));
          mv = fmaxf(mv, fmaf((float)(U.z >> 16),     -kdec, hB.z));
          mv = fmaxf(mv, fmaf((float)(U.w & 0xFFFFu), -kdec, hA.w));
          mv = fmaxf(mv, fmaf((float)(U.w >> 16),     -kdec, hB.w));
        }
        #pragma unroll
        for (int off = 32; off >= 1; off >>= 1)
          mv = fmaxf(mv, __shfl_xor(mv, off, 64));
        mh[r] = mv;
        float sv = 0.0f;
        for (int t = 0; t < 4; ++t) {
          const int j = t * 256 + (lane << 2);
          const float4 hA = *(const float4*)&Hs[j];
          const float4 hB = *(const float4*)&Hs[j + 1024];
          const uint4 U = mrow4[(r << 8) + t * 64 + lane];
          const float m8 = mh[r];
          sv += __builtin_amdgcn_exp2f(fmaf((float)(U.x & 0xFFFFu), -kdec, hA.x - m8))
              + __builtin_amdgcn_exp2f(fmaf((float)(U.x >> 16),     -kdec, hB.x - m8))
              + __builtin_amdgcn_exp2f(fmaf((float)(U.y & 0xFFFFu), -kdec, hA.y - m8))
              + __builtin_amdgcn_exp2f(fmaf((float)(U.y >> 16),     -kdec, hB.y - m8))
              + __builtin_amdgcn_exp2f(fmaf((float)(U.z & 0xFFFFu), -kdec, hA.z - m8))
              + __builtin_amdgcn_exp2f(fmaf((float)(U.z >> 16),     -kdec, hB.z - m8))
              + __builtin_amdgcn_exp2f(fmaf((float)(U.w & 0xFFFFu), -kdec, hA.w - m8))
              + __builtin_amdgcn_exp2f(fmaf((float)(U.w >> 16),     -kdec, hB.w - m8));
        }
        #pragma unroll
        for (int off = 32; off >= 1; off >>= 1)
          sv += __shfl_xor(sv, off, 64);
        ss[r] = sv;
      }
    }
  } else {
    // ---------------- R10 recompute path (proven) ----------------
    float qx[8], qy[8], qz[8], qw[8];
    #pragma unroll
    for (int r = 0; r < 8; ++r) {
      const float4 t4 = rowp[b * NP + i0 + r];
      qx[r] = bcastf(t4.x); qy[r] = bcastf(t4.y);
      qz[r] = bcastf(t4.z); qw[r] = bcastf(t4.w);
    }
    for (int t = 0; t < 16; ++t) {
      float4 p[2]; float h[2];
      #pragma unroll
      for (int cc = 0; cc < 2; ++cc) {
        const int j = (t * 2 + cc) * 64 + lane;
        p[cc] = Pts[j];
        h[cc] = Hs[j];
      }
      #pragma unroll
      for (int r = 0; r < 8; ++r) {
        #pragma unroll
        for (int cc = 0; cc < 2; ++cc) {
          const float dt = fmaf(qx[r], p[cc].x,
                            fmaf(qy[r], p[cc].y,
                             fmaf(qz[r], p[cc].z, qw[r] * p[cc].w)));
          const float u  = fmaxf(1.0f - fabsf(dt), 1e-6f);
          const float sq = __builtin_amdgcn_sqrtf(u);
          const float pl = fmaf(fmaf(fmaf(B3, u, B2), u, B1), u, B0);
          const float v  = fmaf(sq, -pl, h[cc]);
          ss[r] += __builtin_amdgcn_exp2f(v - mh[r]);
        }
      }
    }
    #pragma unroll
    for (int r = 0; r < 8; ++r) {
      float sv = ss[r];
      #pragma unroll
      for (int off = 32; off >= 1; off >>= 1)
        sv += __shfl_xor(sv, off, 64);
      ss[r] = sv;
    }
    #pragma unroll
    for (int r = 0; r < 8; ++r) {
      const bool good = (ss[r] >= 8.6736174e-19f) && (ss[r] <= 1.1529215e18f);
      if (!good) {
        float mv = -3.0e38f;
        for (int t = 0; t < 32; ++t) {
          const int j = t * 64 + lane;
          const float4 p = Pts[j];
          const float dt = fmaf(qx[r], p.x,
                            fmaf(qy[r], p.y, fmaf(qz[r], p.z, qw[r] * p.w)));
          const float u  = fmaxf(1.0f - fabsf(dt), 1e-6f);
          const float sq = __builtin_amdgcn_sqrtf(u);
          const float pl = fmaf(fmaf(fmaf(B3, u, B2), u, B1), u, B0);
          mv = fmaxf(mv, fmaf(sq, -pl, Hs[j]));
        }
        #pragma unroll
        for (int off = 32; off >= 1; off >>= 1)
          mv = fmaxf(mv, __shfl_xor(mv, off, 64));
        mh[r] = mv;
        float sv = 0.0f;
        for (int t = 0; t < 32; ++t) {
          const int j = t * 64 + lane;
          const float4 p = Pts[j];
          const float dt = fmaf(qx[r], p.x,
                            fmaf(qy[r], p.y, fmaf(qz[r], p.z, qw[r] * p.w)));
          const float u  = fmaxf(1.0f - fabsf(dt), 1e-6f);
          const float sq = __builtin_amdgcn_sqrtf(u);
          const float pl = fmaf(fmaf(fmaf(B3, u, B2), u, B1), u, B0);
          sv += __builtin_amdgcn_exp2f(fmaf(sq, -pl, Hs[j]) - mh[r]);
        }
        #pragma unroll
        for (int off = 32; off >= 1; off >>= 1)
          sv += __shfl_xor(sv, off, 64);
        ss[r] = sv;
      }
    }
  }

  if (lane == 0) {
    #pragma unroll
    for (int r = 0; r < 8; ++r) {
      float res = -eps * 0.69314718055994531f
                * (mh[r] + __builtin_amdgcn_logf(ss[r]));
      if (use_avg) res = 0.5f * (pot_old[oidx + r] + res);
      pot_new[oidx + r] = res;
    }
  }
}

__global__ __launch_bounds__(256) void loss_kernel(
    const float* __restrict__ pot, const float* __restrict__ wx,
    const float* __restrict__ wy, float* __restrict__ out)
{
  const int tid = threadIdx.x;
  double acc = 0.0;
  for (int idx = tid; idx < NPOT; idx += 256) {
    acc += (double)wx[idx] * ((double)pot[0 * NPOT + idx] - (double)pot[2 * NPOT + idx]);
    acc += (double)wy[idx] * ((double)pot[1 * NPOT + idx] - (double)pot[3 * NPOT + idx]);
  }
  #pragma unroll
  for (int off = 32; off >= 1; off >>= 1)
    acc += __shfl_xor(acc, off, 64);
  __shared__ double wsum[4];
  if ((tid & 63) == 0) wsum[tid >> 6] = acc;
  __syncthreads();
  if (tid == 0)
    out[0] = (float)((wsum[0] + wsum[1] + wsum[2] + wsum[3]) / (double)BATCH);
}

extern "C" void kernel_launch(void* const* d_in, const int* in_sizes, int n_in,
                              void* d_out, int out_size, void* d_ws, size_t ws_size,
                              hipStream_t stream)
{
  const float* x  = (const float*)d_in[0];
  const float* y  = (const float*)d_in[1];
  const float* wx = (const float*)d_in[2];
  const float* wy = (const float*)d_in[3];

  const size_t potBytes = (size_t)2 * 4 * NPOT * 4;   // 524,288
  int n_mats = 0;
  if      (ws_size >= 3 * MAT_BYTES + potBytes) n_mats = 3;
  else if (ws_size >= 2 * MAT_BYTES + potBytes) n_mats = 2;
  else if (ws_size >= 1 * MAT_BYTES + potBytes) n_mats = 1;

  unsigned int* mats = (unsigned int*)d_ws;
  float* pot[2];
  pot[0] = (float*)((char*)d_ws + (size_t)n_mats * MAT_BYTES);
  pot[1] = pot[0] + 4 * NPOT;

  // geomloss epsilon_schedule(p=2, diameter=3.15, blur=0.01, scaling=0.5)
  double eps_list[16]; int ne = 0;
  eps_list[ne++] = 3.15 * 3.15;
  const double stop = 2.0 * log(0.01), step = 2.0 * log(0.5);
  for (double e = 2.0 * log(3.15); e > stop; e += step) eps_list[ne++] = exp(e);
  eps_list[ne++] = 0.01 * 0.01;   // ne == 11

  const double LOG2E = 1.4426950408889634;
  const double PI    = 3.14159265358979323846;
  // acos(d) ~= sqrt(u)*(b0 + b1 u + b2 u^2 + b3 u^3), u = 1-d, |err|<=6.7e-5
  const double b0 = 1.4141461, b1 = 0.1197803, b2 = 0.0180731, b3 = 0.0187293;
  const dim3 grid(1024), blkPass(512), blkLoss(256);
  int cur = 0;

  if (n_mats > 0) {
    const double S2 = 2.0 * 65535.0 / PI;   // fold 2*65535/pi into coeffs
    hipLaunchKernelGGL(precompute_mats, dim3(n_mats * 256), blkPass, 0, stream,
        x, y, mats,
        (float)(b0 * S2), (float)(b1 * S2), (float)(b2 * S2), (float)(b3 * S2));
  }

  auto launch_pass = [&](double e, float c1f, float seedf, int avg) {
    const double sc = 2.0 * LOG2E / e;
    const double kd = (PI / 65535.0) * (LOG2E / e);
    hipLaunchKernelGGL(sink_pass_r14, grid, blkPass, 0, stream,
        x, y, wx, wy, mats, n_mats, pot[cur], pot[1 - cur],
        (float)e, c1f, seedf, (float)kd,
        (float)(b0 * sc), (float)(b1 * sc), (float)(b2 * sc), (float)(b3 * sc), avg);
    cur ^= 1;
  };

  // init pass: no potential in h, m_hat = 0, replace-mode
  launch_pass(eps_list[0], 0.0f, 0.0f, 0);
  // annealing loop, averaging update
  for (int k = 0; k < ne; ++k) {
    const double e = eps_list[k];
    launch_pass(e, (float)(LOG2E / e), (float)(-LOG2E / e), 1);
  }
  // final extrapolation, replace-mode
  {
    const double e = eps_list[ne - 1];
    launch_pass(e, (float)(LOG2E / e), (float)(-LOG2E / e), 0);
  }

  hipLaunchKernelGGL(loss_kernel, dim3(1), blkLoss, 0, stream,
      pot[cur], wx, wy, (float*)d_out);
}